// Round 5
// baseline (1413.300 us; speedup 1.0000x reference)
//
#include <hip/hip_runtime.h>
#include <hip/hip_bf16.h>
#include <math.h>

#define NN 20000
#define EE 320000
#define DD 256
#define TT 8
#define RR 8
#define HH 8
#define LLAYERS 2
#define RELN (LLAYERS * RR * HH * 1024)   // per side (131072)

typedef __attribute__((ext_vector_type(8))) short short8;
typedef __attribute__((ext_vector_type(4))) float f32x4;
typedef __attribute__((ext_vector_type(4))) unsigned short us4;

__device__ __forceinline__ float b2f(unsigned short u) {
    return __uint_as_float(((unsigned int)u) << 16);
}
__device__ __forceinline__ unsigned short f2b(float f) {
    unsigned int x = __float_as_uint(f);
    unsigned int r = (x + 0x7fffu + ((x >> 16) & 1u)) >> 16;
    return (unsigned short)r;
}

// ---------- one-shot prep: nf conv + rel convs (both plain, contiguous dst) ----------
__global__ void k_prep(const float* __restrict__ nf, const float* __restrict__ rA,
                       const float* __restrict__ rM,
                       unsigned short* __restrict__ nf_bf, unsigned short* __restrict__ relAll) {
    int idx = blockIdx.x * 256 + threadIdx.x;
    const int n0 = NN * 256;
    if (idx < n0) { nf_bf[idx] = f2b(nf[idx]); return; }
    idx -= n0;
    if (idx < RELN) { relAll[idx] = f2b(rA[idx]); return; }
    idx -= RELN;
    if (idx < RELN) relAll[RELN + idx] = f2b(rM[idx]);
}

// ---------- all weight transposes in one kernel ----------
__global__ void k_transpose_all(const float* __restrict__ adW, const float* __restrict__ kW,
                                const float* __restrict__ qW, const float* __restrict__ vW,
                                const float* __restrict__ aW, unsigned short* __restrict__ out) {
    __shared__ float tile[32][33];
    int z = blockIdx.z;
    const float* ip;
    if (z < 8) ip = adW + (size_t)z * 65536;
    else if (z < 24) ip = kW + (size_t)(z - 8) * 65536;
    else if (z < 40) ip = qW + (size_t)(z - 24) * 65536;
    else if (z < 56) ip = vW + (size_t)(z - 40) * 65536;
    else ip = aW + (size_t)(z - 56) * 65536;
    unsigned short* op = out + (size_t)z * 65536;
    int ox = blockIdx.x * 32, dy = blockIdx.y * 32;
    int tx = threadIdx.x, ty = threadIdx.y; // 32 x 8
#pragma unroll
    for (int r = 0; r < 4; r++) tile[ty + 8 * r][tx] = ip[(size_t)(dy + ty + 8 * r) * 256 + ox + tx];
    __syncthreads();
#pragma unroll
    for (int r = 0; r < 4; r++) op[(size_t)(ox + ty + 8 * r) * 256 + dy + tx] = f2b(tile[tx][ty + 8 * r]);
}

// ---------- graph build ----------
__global__ void k_build1(const int* __restrict__ ei, const int* __restrict__ nt,
                         int* __restrict__ deg, int* __restrict__ tcnt,
                         int* __restrict__ rank) {
    int i = blockIdx.x * 256 + threadIdx.x;
    if (i < EE) rank[i] = atomicAdd(&deg[ei[EE + i]], 1);
    if (i < NN) atomicAdd(&tcnt[nt[i]], 1);
}

__global__ void k_scan(const int* __restrict__ deg, int* __restrict__ off,
                       const int* __restrict__ tcnt, int* __restrict__ toff) {
    __shared__ int partial[256];
    int tid = threadIdx.x;
    const int chunk = (NN + 255) / 256;
    int s0 = tid * chunk;
    int s1 = s0 + chunk; if (s1 > NN) s1 = NN;
    int sum = 0;
    for (int i = s0; i < s1; i++) sum += deg[i];
    partial[tid] = sum;
    __syncthreads();
    for (int d = 1; d < 256; d <<= 1) {
        int t = (tid >= d) ? partial[tid - d] : 0;
        __syncthreads();
        partial[tid] += t;
        __syncthreads();
    }
    int run = partial[tid] - sum;  // exclusive prefix
    for (int i = s0; i < s1; i++) { off[i] = run; run += deg[i]; }
    if (tid == 255) off[NN] = run;
    if (tid == 0) {
        int a = 0;
        for (int t = 0; t < TT; t++) { toff[t] = a; a += tcnt[t]; }
        toff[TT] = a;
    }
}

// atomic-free CSR fill: one packed 16B scatter per edge {src|et<<16, ew, dst, 0}
__global__ void k_build2(const int* __restrict__ ei, const int* __restrict__ et,
                         const float* __restrict__ ew,
                         const int* __restrict__ nt, const int* __restrict__ off,
                         const int* __restrict__ toff, const int* __restrict__ rank,
                         int* __restrict__ tcur, int4* __restrict__ csr,
                         int* __restrict__ epos, int* __restrict__ nlist) {
    int i = blockIdx.x * 256 + threadIdx.x;
    if (i < EE) {
        int d = ei[EE + i];
        int p = off[d] + rank[i];
        epos[i] = p;
        int4 pk;
        pk.x = ei[i] | (et[i] << 16);
        pk.y = __float_as_int(ew[i]);
        pk.z = d;
        pk.w = 0;
        csr[p] = pk;
    }
    if (i < NN) {
        int t = nt[i];
        int pos = atomicAdd(&tcur[t], 1);
        nlist[toff[t] + pos] = i;
    }
}

// ---------- type-grouped GEMM (64 rows x 256 cols, K=256) ----------
#define LDA 264

__device__ __forceinline__ void gemm_core(const unsigned short* A_l, const unsigned short* wt,
                                          int colbase, int l15, int l4, f32x4 acc[4][4]) {
    f32x4 zf = {0.f, 0.f, 0.f, 0.f};
#pragma unroll
    for (int a = 0; a < 4; a++)
#pragma unroll
        for (int b = 0; b < 4; b++) acc[a][b] = zf;
    for (int ks = 0; ks < 8; ks++) {
        int k0 = ks * 32;
        short8 af[4], bfr[4];
#pragma unroll
        for (int rb = 0; rb < 4; rb++)
            af[rb] = *(const short8*)(A_l + (rb * 16 + l15) * LDA + k0 + 8 * l4);
#pragma unroll
        for (int cb = 0; cb < 4; cb++)
            bfr[cb] = *(const short8*)(wt + (size_t)(colbase + cb * 16 + l15) * 256 + k0 + 8 * l4);
#pragma unroll
        for (int rb = 0; rb < 4; rb++)
#pragma unroll
            for (int cb = 0; cb < 4; cb++)
                acc[rb][cb] = __builtin_amdgcn_mfma_f32_16x16x32_bf16(af[rb], bfr[cb], acc[rb][cb], 0, 0, 0);
    }
}

template <int MODE>
__global__ __launch_bounds__(256) void k_gemm(
    const unsigned short* __restrict__ Abf,
    const unsigned short* __restrict__ Wt,
    const float* __restrict__ bias,
    const int* __restrict__ nlist, const int* __restrict__ toff,
    unsigned short* __restrict__ out_bf, float* out_f32,
    const float* x_in, const float* __restrict__ skipv,
    const float* __restrict__ lng, const float* __restrict__ lnb)
{
    __shared__ unsigned short A_l[64 * LDA];
    __shared__ int nid[64];
    __shared__ float redS[64 * 4];
    __shared__ float redQ[64 * 4];
    __shared__ float meanl[64];
    __shared__ float invl[64];

    int t = blockIdx.y;
    int g0 = toff[t], g1 = toff[t + 1];
    int base = blockIdx.x * 64;
    int cnt = g1 - g0 - base;
    if (cnt <= 0) return;
    if (cnt > 64) cnt = 64;
    int tid = threadIdx.x;
    if (tid < 64) nid[tid] = (tid < cnt) ? nlist[g0 + base + tid] : -1;
    __syncthreads();

#pragma unroll
    for (int it = 0; it < 8; it++) {
        int id = it * 256 + tid;
        int row = id >> 5, c8 = id & 31;
        short8 v = {};
        int nd = nid[row];
        if (nd >= 0) v = *(const short8*)(Abf + (size_t)nd * 256 + c8 * 8);
        *(short8*)(A_l + row * LDA + c8 * 8) = v;
    }
    __syncthreads();

    int lane = tid & 63, wave = tid >> 6;
    int colbase = wave * 64;
    int l15 = lane & 15, l4 = lane >> 4;
    f32x4 acc[4][4];
    gemm_core(A_l, Wt + (size_t)t * 65536, colbase, l15, l4, acc);

    if (MODE == 0) {
#pragma unroll
        for (int rb = 0; rb < 4; rb++) {
#pragma unroll
            for (int j = 0; j < 4; j++) {
                int r = rb * 16 + l4 * 4 + j;
                int nd = nid[r];
                if (nd < 0) continue;
#pragma unroll
                for (int cb = 0; cb < 4; cb++) {
                    int col = colbase + cb * 16 + l15;
                    float v = tanhf(acc[rb][cb][j] + bias[t * 256 + col]);
                    out_f32[(size_t)nd * 256 + col] = v;
                    out_bf[(size_t)nd * 256 + col] = f2b(v);
                }
            }
        }
    } else {
        float alpha = 1.f / (1.f + __expf(-skipv[t]));
#pragma unroll
        for (int rb = 0; rb < 4; rb++) {
#pragma unroll
            for (int j = 0; j < 4; j++) {
                int r = rb * 16 + l4 * 4 + j;
                int nd = nid[r];
                float s = 0.f, q = 0.f;
#pragma unroll
                for (int cb = 0; cb < 4; cb++) {
                    int col = colbase + cb * 16 + l15;
                    float v = acc[rb][cb][j] + bias[t * 256 + col];
                    float xi = (nd >= 0) ? x_in[(size_t)nd * 256 + col] : 0.f;
                    float o = v * alpha + xi * (1.f - alpha);
                    acc[rb][cb][j] = o;
                    s += o;
                    q += o * o;
                }
#pragma unroll
                for (int m = 1; m < 16; m <<= 1) {
                    s += __shfl_xor(s, m, 16);
                    q += __shfl_xor(q, m, 16);
                }
                if (l15 == 0) { redS[r * 4 + wave] = s; redQ[r * 4 + wave] = q; }
            }
        }
        __syncthreads();
        if (tid < 64) {
            float s = redS[tid * 4] + redS[tid * 4 + 1] + redS[tid * 4 + 2] + redS[tid * 4 + 3];
            float q = redQ[tid * 4] + redQ[tid * 4 + 1] + redQ[tid * 4 + 2] + redQ[tid * 4 + 3];
            float mean = s * (1.f / 256.f);
            float var = q * (1.f / 256.f) - mean * mean;
            meanl[tid] = mean;
            invl[tid] = rsqrtf(var + 1e-5f);
        }
        __syncthreads();
#pragma unroll
        for (int rb = 0; rb < 4; rb++) {
#pragma unroll
            for (int j = 0; j < 4; j++) {
                int r = rb * 16 + l4 * 4 + j;
                int nd = nid[r];
                if (nd < 0) continue;
                float mean = meanl[r], inv = invl[r];
#pragma unroll
                for (int cb = 0; cb < 4; cb++) {
                    int col = colbase + cb * 16 + l15;
                    float o = (acc[rb][cb][j] - mean) * inv * lng[t * 256 + col] + lnb[t * 256 + col];
                    out_f32[(size_t)nd * 256 + col] = o;
                    out_bf[(size_t)nd * 256 + col] = f2b(o);
                }
            }
        }
    }
}

// fused k/q/v: stage A once, run 3 weight sets
__global__ __launch_bounds__(256) void k_gemm3(
    const unsigned short* __restrict__ Abf,
    const unsigned short* __restrict__ Wt0, const unsigned short* __restrict__ Wt1,
    const unsigned short* __restrict__ Wt2,
    const float* __restrict__ b0, const float* __restrict__ b1, const float* __restrict__ b2,
    const int* __restrict__ nlist, const int* __restrict__ toff,
    unsigned short* __restrict__ o0, unsigned short* __restrict__ o1,
    unsigned short* __restrict__ o2)
{
    __shared__ unsigned short A_l[64 * LDA];
    __shared__ int nid[64];

    int t = blockIdx.y;
    int g0 = toff[t], g1 = toff[t + 1];
    int base = blockIdx.x * 64;
    int cnt = g1 - g0 - base;
    if (cnt <= 0) return;
    if (cnt > 64) cnt = 64;
    int tid = threadIdx.x;
    if (tid < 64) nid[tid] = (tid < cnt) ? nlist[g0 + base + tid] : -1;
    __syncthreads();

#pragma unroll
    for (int it = 0; it < 8; it++) {
        int id = it * 256 + tid;
        int row = id >> 5, c8 = id & 31;
        short8 v = {};
        int nd = nid[row];
        if (nd >= 0) v = *(const short8*)(Abf + (size_t)nd * 256 + c8 * 8);
        *(short8*)(A_l + row * LDA + c8 * 8) = v;
    }
    __syncthreads();

    int lane = tid & 63, wave = tid >> 6;
    int colbase = wave * 64;
    int l15 = lane & 15, l4 = lane >> 4;
    const unsigned short* Wts[3] = {Wt0, Wt1, Wt2};
    const float* bs[3] = {b0, b1, b2};
    unsigned short* os[3] = {o0, o1, o2};
#pragma unroll
    for (int w = 0; w < 3; w++) {
        f32x4 acc[4][4];
        gemm_core(A_l, Wts[w] + (size_t)t * 65536, colbase, l15, l4, acc);
#pragma unroll
        for (int rb = 0; rb < 4; rb++) {
#pragma unroll
            for (int j = 0; j < 4; j++) {
                int r = rb * 16 + l4 * 4 + j;
                int nd = nid[r];
                if (nd < 0) continue;
#pragma unroll
                for (int cb = 0; cb < 4; cb++) {
                    int col = colbase + cb * 16 + l15;
                    os[w][(size_t)nd * 256 + col] = f2b(acc[rb][cb][j] + bs[w][t * 256 + col]);
                }
            }
        }
    }
}

// ---------- q-side relation transform; h-pair blocks for 128B-merged writes ----------
__global__ __launch_bounds__(256) void k_rt(
    const unsigned short* __restrict__ qb,    // [NN][256] bf16
    const unsigned short* __restrict__ relA,  // [R][H][32][32] bf16 (layer offset applied)
    unsigned short* __restrict__ qrt)         // [NN][R][H][32] bf16
{
    int tid = threadIdx.x;
    int lane = tid & 63, wave = tid >> 6;
    int l15 = lane & 15, l4 = lane >> 4;
    int hp = blockIdx.y;                      // h in {2hp, 2hp+1}
    int n = blockIdx.x * 64 + wave * 16 + l15;
    bool ok = (n < NN);
    for (int r = 0; r < RR; r++) {
#pragma unroll
        for (int hh = 0; hh < 2; hh++) {
            int h = hp * 2 + hh;
            short8 bfrag = {};
            if (ok) bfrag = *(const short8*)(qb + (size_t)n * 256 + h * 32 + 8 * l4);
            const unsigned short* ap = relA + ((size_t)(r * HH + h)) * 1024;
            short8 a0 = *(const short8*)(ap + l15 * 32 + 8 * l4);
            short8 a1 = *(const short8*)(ap + (16 + l15) * 32 + 8 * l4);
            f32x4 c0 = {0.f, 0.f, 0.f, 0.f}, c1 = {0.f, 0.f, 0.f, 0.f};
            c0 = __builtin_amdgcn_mfma_f32_16x16x32_bf16(a0, bfrag, c0, 0, 0, 0);
            c1 = __builtin_amdgcn_mfma_f32_16x16x32_bf16(a1, bfrag, c1, 0, 0, 0);
            if (ok) {
                size_t ob = (((size_t)n * RR + r) * HH + h) * 32;
                us4 p0, p1;
#pragma unroll
                for (int j = 0; j < 4; j++) { p0[j] = f2b(c0[j]); p1[j] = f2b(c1[j]); }
                *(us4*)(qrt + ob + l4 * 4) = p0;
                *(us4*)(qrt + ob + 16 + l4 * 4) = p1;
            }
        }
    }
}

// ---------- edge scores over CSR positions (coalesced writes) ----------
__global__ void k_score(const unsigned short* __restrict__ kbf,
                        const unsigned short* __restrict__ qrt,
                        const int4* __restrict__ csr, const float* __restrict__ pri,
                        float* __restrict__ sc)
{
    int idx = blockIdx.x * 256 + threadIdx.x;
    if (idx >= EE * HH) return;
    int p = idx >> 3, h = idx & 7;
    int4 pk = csr[p];
    int s = pk.x & 0xffff, r = (pk.x >> 16) & 7;
    float w = __int_as_float(pk.y);
    int d = pk.z;
    const short8* kp = (const short8*)(kbf + (size_t)s * 256 + h * 32);
    const short8* qp = (const short8*)(qrt + (((size_t)d * RR + r) * HH + h) * 32);
    float acc = 0.f;
#pragma unroll
    for (int c = 0; c < 4; c++) {
        short8 a = kp[c], b = qp[c];
#pragma unroll
        for (int j = 0; j < 8; j++)
            acc += b2f((unsigned short)a[j]) * b2f((unsigned short)b[j]);
    }
    sc[idx] = acc * pri[r * HH + h] * 0.17677669529663687f * w;
}

// ---------- softmax + raw-v aggregate per relation + in-block transform + gelu ----------
// block = 256 threads = 8 h-groups; 8 dst nodes per block; transform in 2 passes of 4.
__global__ __launch_bounds__(256) void k_aggt(
    const float* __restrict__ sc,           // [CSR][8] scores
    const unsigned short* __restrict__ vb,  // [NN][256] raw v (bias applied)
    const int4* __restrict__ csr,
    const int* __restrict__ off,
    const unsigned short* __restrict__ relM,// [R][H][32][32] bf16, layout [d][e']
    unsigned short* __restrict__ gbf,
    float* __restrict__ smaxg, float* __restrict__ ssumg)
{
    __shared__ float aggL[4][RR][HH][32];   // 32 KB
    __shared__ float den_l[4][HH];

    int tid = threadIdx.x;
    int h = tid >> 5, i = tid & 31;
    int nbase = blockIdx.x * 8;
    const int* csrx = (const int*)csr;

    for (int g = 0; g < 2; g++) {
        // --- edge phase: 4 nodes, all in registers ---
        for (int nd = 0; nd < 4; nd++) {
            int n = nbase + g * 4 + nd;
            int t0 = off[n], cnt = off[n + 1] - t0;
            float smax = -INFINITY;
            for (int ii = i; ii < cnt; ii += 32)
                smax = fmaxf(smax, sc[(size_t)(t0 + ii) * 8 + h]);
#pragma unroll
            for (int mm = 16; mm >= 1; mm >>= 1) smax = fmaxf(smax, __shfl_xor(smax, mm, 32));

            float psum = 0.f;
            float aggv[8] = {0.f, 0.f, 0.f, 0.f, 0.f, 0.f, 0.f, 0.f};
            for (int ii = 0; ii < cnt; ii++) {
                int pkx = csrx[(size_t)(t0 + ii) * 4];     // broadcast
                int src = pkx & 0xffff, r = (pkx >> 16) & 7;
                float p = __expf(sc[(size_t)(t0 + ii) * 8 + h] - smax);  // uniform in group
                psum += p;
                float v = b2f(vb[(size_t)src * 256 + h * 32 + i]);
#pragma unroll
                for (int rr = 0; rr < 8; rr++)
                    aggv[rr] = fmaf((r == rr) ? p : 0.f, v, aggv[rr]);
            }
            if (i == 0) {
                smaxg[n * 8 + h] = smax;
                ssumg[n * 8 + h] = psum;
                den_l[nd][h] = psum + 1e-9f;
            }
#pragma unroll
            for (int rr = 0; rr < 8; rr++) aggL[nd][rr][h][i] = aggv[rr];
        }
        __syncthreads();
        // --- transform phase: out[h][e'=i] = sum_r sum_d aggL[r][h][d] * relM[r,h,d,e'] ---
        float outv[4] = {0.f, 0.f, 0.f, 0.f};
        for (int r = 0; r < RR; r++) {
#pragma unroll 8
            for (int d = 0; d < 32; d++) {
                float w = b2f(relM[(((size_t)(r * HH + h) * 32 + d) << 5) + i]);
#pragma unroll
                for (int nd = 0; nd < 4; nd++)
                    outv[nd] = fmaf(aggL[nd][r][h][d], w, outv[nd]);
            }
        }
#pragma unroll
        for (int nd = 0; nd < 4; nd++) {
            int n = nbase + g * 4 + nd;
            float a = outv[nd] / den_l[nd][h];
            float gl = 0.5f * a * (1.f + tanhf(0.7978845608028654f * (a + 0.044715f * a * a * a)));
            gbf[(size_t)n * 256 + tid] = f2b(gl);
        }
        __syncthreads();   // aggL reused next group
    }
}

// ---------- attention output (last layer) ----------
__global__ void k_att(const float* __restrict__ sc, const int* __restrict__ ei,
                      const int* __restrict__ epos,
                      const float* __restrict__ smaxg, const float* __restrict__ ssumg,
                      float* __restrict__ att)
{
    int idx = blockIdx.x * 256 + threadIdx.x;
    if (idx >= EE * HH) return;
    int e = idx >> 3, h = idx & 7;
    int d = ei[EE + e];
    att[idx] = __expf(sc[(size_t)epos[e] * 8 + h] - smaxg[d * 8 + h]) / (ssumg[d * 8 + h] + 1e-9f);
}

extern "C" void kernel_launch(void* const* d_in, const int* in_sizes, int n_in,
                              void* d_out, int out_size, void* d_ws, size_t ws_size,
                              hipStream_t stream)
{
    const float* nf = (const float*)d_in[0];
    const int* ntyp = (const int*)d_in[1];
    const float* ew = (const float*)d_in[2];
    const int* ei = (const int*)d_in[3];
    const int* ety = (const int*)d_in[4];
    const float* adW = (const float*)d_in[5];
    const float* adb = (const float*)d_in[6];
    const float* kW = (const float*)d_in[7];
    const float* kb = (const float*)d_in[8];
    const float* qW = (const float*)d_in[9];
    const float* qb = (const float*)d_in[10];
    const float* vW = (const float*)d_in[11];
    const float* vb = (const float*)d_in[12];
    const float* aW = (const float*)d_in[13];
    const float* ab = (const float*)d_in[14];
    const float* pri = (const float*)d_in[15];
    const float* rA = (const float*)d_in[16];
    const float* rM = (const float*)d_in[17];
    const float* skp = (const float*)d_in[18];
    const float* lng = (const float*)d_in[19];
    const float* lnb = (const float*)d_in[20];

    float* x_out = (float*)d_out;
    float* att_out = x_out + (size_t)NN * 256;

    char* wsb = (char*)d_ws;
    size_t o = 0;
    auto take = [&](size_t bytes) -> void* {
        size_t r = (o + 255) & ~(size_t)255;
        o = r + bytes;
        return (void*)(wsb + r);
    };
    unsigned short* nf_bf = (unsigned short*)take((size_t)NN * 256 * 2);
    unsigned short* x_bf = (unsigned short*)take((size_t)NN * 256 * 2);
    unsigned short* kb16 = (unsigned short*)take((size_t)NN * 256 * 2);
    unsigned short* qb16 = (unsigned short*)take((size_t)NN * 256 * 2);
    unsigned short* vb16 = (unsigned short*)take((size_t)NN * 256 * 2);
    unsigned short* gb16 = (unsigned short*)take((size_t)NN * 256 * 2);
    unsigned short* qrt = (unsigned short*)take((size_t)NN * RR * HH * 32 * 2);
    float* scores = (float*)take((size_t)EE * HH * 4);
    float* smaxg = (float*)take((size_t)NN * HH * 4);
    float* ssumg = (float*)take((size_t)NN * HH * 4);
    unsigned short* Wt_all = (unsigned short*)take((size_t)72 * 65536 * 2);
    unsigned short* adWt = Wt_all;
    unsigned short* kWt = Wt_all + (size_t)8 * 65536;
    unsigned short* qWt = Wt_all + (size_t)24 * 65536;
    unsigned short* vWt = Wt_all + (size_t)40 * 65536;
    unsigned short* aWt = Wt_all + (size_t)56 * 65536;
    unsigned short* relAll = (unsigned short*)take((size_t)2 * RELN * 2);  // [relA | relM]
    int* zblock = (int*)take((size_t)(NN + 2 * TT) * 4);
    int* deg = zblock;
    int* tcnt = zblock + NN;
    int* tcur = zblock + NN + TT;
    int* rank = (int*)take((size_t)EE * 4);
    int* off = (int*)take((size_t)(NN + 1) * 4);
    int4* csr = (int4*)take((size_t)EE * 16);
    int* epos = (int*)take((size_t)EE * 4);
    int* toff = (int*)take((TT + 1) * 4);
    int* nlist = (int*)take((size_t)NN * 4);
    if (o > ws_size) return;  // workspace insufficient — fail visibly

    hipMemsetAsync(zblock, 0, (size_t)(NN + 2 * TT) * 4, stream);

    int ptot = NN * 256 + 2 * RELN;
    k_prep<<<(ptot + 255) / 256, 256, 0, stream>>>(nf, rA, rM, nf_bf, relAll);
    k_transpose_all<<<dim3(8, 8, 72), dim3(32, 8), 0, stream>>>(adW, kW, qW, vW, aW, Wt_all);

    k_build1<<<(EE + 255) / 256, 256, 0, stream>>>(ei, ntyp, deg, tcnt, rank);
    k_scan<<<1, 256, 0, stream>>>(deg, off, tcnt, toff);
    k_build2<<<(EE + 255) / 256, 256, 0, stream>>>(ei, ety, ew, ntyp, off, toff, rank,
                                                   tcur, csr, epos, nlist);

    dim3 ggrid((NN + 63) / 64, TT);
    k_gemm<0><<<ggrid, 256, 0, stream>>>(nf_bf, adWt, adb, nlist, toff,
                                         x_bf, x_out, nullptr, nullptr, nullptr, nullptr);

    dim3 rgrid((NN + 63) / 64, 4);
    int egrid = (EE * HH + 255) / 256;
    for (int l = 0; l < LLAYERS; l++) {
        const unsigned short* relA_l = relAll + (size_t)l * RR * HH * 1024;
        const unsigned short* relM_l = relAll + (size_t)RELN + (size_t)l * RR * HH * 1024;
        k_gemm3<<<ggrid, 256, 0, stream>>>(x_bf,
                                           kWt + (size_t)l * TT * 65536, qWt + (size_t)l * TT * 65536,
                                           vWt + (size_t)l * TT * 65536,
                                           kb + (size_t)l * TT * 256, qb + (size_t)l * TT * 256,
                                           vb + (size_t)l * TT * 256,
                                           nlist, toff, kb16, qb16, vb16);
        k_rt<<<rgrid, 256, 0, stream>>>(qb16, relA_l, qrt);
        k_score<<<egrid, 256, 0, stream>>>(kb16, qrt, csr, pri + (size_t)l * RR * HH, scores);
        k_aggt<<<NN / 8, 256, 0, stream>>>(scores, vb16, csr, off, relM_l,
                                           gb16, smaxg, ssumg);
        if (l == LLAYERS - 1)
            k_att<<<egrid, 256, 0, stream>>>(scores, ei, epos, smaxg, ssumg, att_out);
        k_gemm<2><<<ggrid, 256, 0, stream>>>(gb16, aWt + (size_t)l * TT * 65536, ab + (size_t)l * TT * 256,
                                             nlist, toff, x_bf, x_out, x_out,
                                             skp + (size_t)l * TT, lng + (size_t)l * TT * 256, lnb + (size_t)l * TT * 256);
    }
}

// Round 6
// 715.363 us; speedup vs baseline: 1.9756x; 1.9756x over previous
//
#include <hip/hip_runtime.h>
#include <hip/hip_bf16.h>
#include <math.h>

#define NN 20000
#define EE 320000
#define DD 256
#define TT 8
#define RR 8
#define HH 8
#define LLAYERS 2
#define RELN (LLAYERS * RR * HH * 1024)

typedef __attribute__((ext_vector_type(8))) short short8;
typedef __attribute__((ext_vector_type(4))) float f32x4;
typedef __attribute__((ext_vector_type(4))) unsigned short us4;

__device__ __forceinline__ float b2f(unsigned short u) {
    return __uint_as_float(((unsigned int)u) << 16);
}
__device__ __forceinline__ unsigned short f2b(float f) {
    unsigned int x = __float_as_uint(f);
    unsigned int r = (x + 0x7fffu + ((x >> 16) & 1u)) >> 16;
    return (unsigned short)r;
}

// ---------- one-shot prep: nf conv + relA conv + relM transposed conv ----------
__global__ void k_prep(const float* __restrict__ nf, const float* __restrict__ rA,
                       const float* __restrict__ rM,
                       unsigned short* __restrict__ nf_bf, unsigned short* __restrict__ relA,
                       unsigned short* __restrict__ relMT) {
    int idx = blockIdx.x * 256 + threadIdx.x;
    const int n0 = NN * 256;
    if (idx < n0) { nf_bf[idx] = f2b(nf[idx]); return; }
    idx -= n0;
    if (idx < RELN) { relA[idx] = f2b(rA[idx]); return; }
    idx -= RELN;
    if (idx < RELN) {
        int g = idx >> 10, loc = idx & 1023;
        int a = loc >> 5, b = loc & 31;
        // relMT[g][e][d] = rM[g][d][e]  (32x32 block transpose)
        relMT[(size_t)g * 1024 + a * 32 + b] = f2b(rM[(size_t)g * 1024 + b * 32 + a]);
    }
}

// ---------- all weight transposes in one kernel ----------
__global__ void k_transpose_all(const float* __restrict__ adW, const float* __restrict__ kW,
                                const float* __restrict__ qW, const float* __restrict__ vW,
                                const float* __restrict__ aW, unsigned short* __restrict__ out) {
    __shared__ float tile[32][33];
    int z = blockIdx.z;
    const float* ip;
    if (z < 8) ip = adW + (size_t)z * 65536;
    else if (z < 24) ip = kW + (size_t)(z - 8) * 65536;
    else if (z < 40) ip = qW + (size_t)(z - 24) * 65536;
    else if (z < 56) ip = vW + (size_t)(z - 40) * 65536;
    else ip = aW + (size_t)(z - 56) * 65536;
    unsigned short* op = out + (size_t)z * 65536;
    int ox = blockIdx.x * 32, dy = blockIdx.y * 32;
    int tx = threadIdx.x, ty = threadIdx.y; // 32 x 8
#pragma unroll
    for (int r = 0; r < 4; r++) tile[ty + 8 * r][tx] = ip[(size_t)(dy + ty + 8 * r) * 256 + ox + tx];
    __syncthreads();
#pragma unroll
    for (int r = 0; r < 4; r++) op[(size_t)(ox + ty + 8 * r) * 256 + dy + tx] = f2b(tile[tx][ty + 8 * r]);
}

// ---------- graph build ----------
__global__ void k_build1(const int* __restrict__ ei, const int* __restrict__ nt,
                         int* __restrict__ deg, int* __restrict__ tcnt,
                         int* __restrict__ rank) {
    int i = blockIdx.x * 256 + threadIdx.x;
    if (i < EE) rank[i] = atomicAdd(&deg[ei[EE + i]], 1);
    if (i < NN) atomicAdd(&tcnt[nt[i]], 1);
}

__global__ void k_scan(const int* __restrict__ deg, int* __restrict__ off,
                       const int* __restrict__ tcnt, int* __restrict__ toff) {
    __shared__ int partial[256];
    int tid = threadIdx.x;
    const int chunk = (NN + 255) / 256;
    int s0 = tid * chunk;
    int s1 = s0 + chunk; if (s1 > NN) s1 = NN;
    int sum = 0;
    for (int i = s0; i < s1; i++) sum += deg[i];
    partial[tid] = sum;
    __syncthreads();
    for (int d = 1; d < 256; d <<= 1) {
        int t = (tid >= d) ? partial[tid - d] : 0;
        __syncthreads();
        partial[tid] += t;
        __syncthreads();
    }
    int run = partial[tid] - sum;  // exclusive prefix
    for (int i = s0; i < s1; i++) { off[i] = run; run += deg[i]; }
    if (tid == 255) off[NN] = run;
    if (tid == 0) {
        int a = 0;
        for (int t = 0; t < TT; t++) { toff[t] = a; a += tcnt[t]; }
        toff[TT] = a;
    }
}

// atomic-free CSR fill: one packed 16B scatter per edge {src|et<<16, ew, dst, e}
__global__ void k_build2(const int* __restrict__ ei, const int* __restrict__ et,
                         const float* __restrict__ ew,
                         const int* __restrict__ nt, const int* __restrict__ off,
                         const int* __restrict__ toff, const int* __restrict__ rank,
                         int* __restrict__ tcur, int4* __restrict__ csr,
                         int* __restrict__ nlist) {
    int i = blockIdx.x * 256 + threadIdx.x;
    if (i < EE) {
        int d = ei[EE + i];
        int p = off[d] + rank[i];
        int4 pk;
        pk.x = ei[i] | (et[i] << 16);
        pk.y = __float_as_int(ew[i]);
        pk.z = d;
        pk.w = i;
        csr[p] = pk;
    }
    if (i < NN) {
        int t = nt[i];
        int pos = atomicAdd(&tcur[t], 1);
        nlist[toff[t] + pos] = i;
    }
}

// ---------- type-grouped GEMM (64 rows x 256 cols, K=256) ----------
#define LDA 264

__device__ __forceinline__ void gemm_core(const unsigned short* A_l, const unsigned short* wt,
                                          int colbase, int l15, int l4, f32x4 acc[4][4]) {
    f32x4 zf = {0.f, 0.f, 0.f, 0.f};
#pragma unroll
    for (int a = 0; a < 4; a++)
#pragma unroll
        for (int b = 0; b < 4; b++) acc[a][b] = zf;
    for (int ks = 0; ks < 8; ks++) {
        int k0 = ks * 32;
        short8 af[4], bfr[4];
#pragma unroll
        for (int rb = 0; rb < 4; rb++)
            af[rb] = *(const short8*)(A_l + (rb * 16 + l15) * LDA + k0 + 8 * l4);
#pragma unroll
        for (int cb = 0; cb < 4; cb++)
            bfr[cb] = *(const short8*)(wt + (size_t)(colbase + cb * 16 + l15) * 256 + k0 + 8 * l4);
#pragma unroll
        for (int rb = 0; rb < 4; rb++)
#pragma unroll
            for (int cb = 0; cb < 4; cb++)
                acc[rb][cb] = __builtin_amdgcn_mfma_f32_16x16x32_bf16(af[rb], bfr[cb], acc[rb][cb], 0, 0, 0);
    }
}

// MODE 0: tanh epilogue -> bf16 (+f32 if out_f32)
// MODE 2: bias + skip-blend (x_in bf16) + LayerNorm -> bf16 (+f32 if out_f32)
template <int MODE>
__global__ __launch_bounds__(256) void k_gemm(
    const unsigned short* __restrict__ Abf,
    const unsigned short* __restrict__ Wt,
    const float* __restrict__ bias,
    const int* __restrict__ nlist, const int* __restrict__ toff,
    unsigned short* __restrict__ out_bf, float* out_f32,
    const unsigned short* x_in, const float* __restrict__ skipv,
    const float* __restrict__ lng, const float* __restrict__ lnb)
{
    __shared__ unsigned short A_l[64 * LDA];
    __shared__ int nid[64];
    __shared__ float redS[64 * 4];
    __shared__ float redQ[64 * 4];
    __shared__ float meanl[64];
    __shared__ float invl[64];

    int t = blockIdx.y;
    int g0 = toff[t], g1 = toff[t + 1];
    int base = blockIdx.x * 64;
    int cnt = g1 - g0 - base;
    if (cnt <= 0) return;
    if (cnt > 64) cnt = 64;
    int tid = threadIdx.x;
    if (tid < 64) nid[tid] = (tid < cnt) ? nlist[g0 + base + tid] : -1;
    __syncthreads();

#pragma unroll
    for (int it = 0; it < 8; it++) {
        int id = it * 256 + tid;
        int row = id >> 5, c8 = id & 31;
        short8 v = {};
        int nd = nid[row];
        if (nd >= 0) v = *(const short8*)(Abf + (size_t)nd * 256 + c8 * 8);
        *(short8*)(A_l + row * LDA + c8 * 8) = v;
    }
    __syncthreads();

    int lane = tid & 63, wave = tid >> 6;
    int colbase = wave * 64;
    int l15 = lane & 15, l4 = lane >> 4;
    f32x4 acc[4][4];
    gemm_core(A_l, Wt + (size_t)t * 65536, colbase, l15, l4, acc);

    if (MODE == 0) {
#pragma unroll
        for (int rb = 0; rb < 4; rb++) {
#pragma unroll
            for (int j = 0; j < 4; j++) {
                int r = rb * 16 + l4 * 4 + j;
                int nd = nid[r];
                if (nd < 0) continue;
#pragma unroll
                for (int cb = 0; cb < 4; cb++) {
                    int col = colbase + cb * 16 + l15;
                    float v = tanhf(acc[rb][cb][j] + bias[t * 256 + col]);
                    out_bf[(size_t)nd * 256 + col] = f2b(v);
                }
            }
        }
    } else {
        float alpha = 1.f / (1.f + __expf(-skipv[t]));
#pragma unroll
        for (int rb = 0; rb < 4; rb++) {
#pragma unroll
            for (int j = 0; j < 4; j++) {
                int r = rb * 16 + l4 * 4 + j;
                int nd = nid[r];
                float s = 0.f, q = 0.f;
#pragma unroll
                for (int cb = 0; cb < 4; cb++) {
                    int col = colbase + cb * 16 + l15;
                    float v = acc[rb][cb][j] + bias[t * 256 + col];
                    float xi = (nd >= 0) ? b2f(x_in[(size_t)nd * 256 + col]) : 0.f;
                    float o = v * alpha + xi * (1.f - alpha);
                    acc[rb][cb][j] = o;
                    s += o;
                    q += o * o;
                }
#pragma unroll
                for (int m = 1; m < 16; m <<= 1) {
                    s += __shfl_xor(s, m, 16);
                    q += __shfl_xor(q, m, 16);
                }
                if (l15 == 0) { redS[r * 4 + wave] = s; redQ[r * 4 + wave] = q; }
            }
        }
        __syncthreads();
        if (tid < 64) {
            float s = redS[tid * 4] + redS[tid * 4 + 1] + redS[tid * 4 + 2] + redS[tid * 4 + 3];
            float q = redQ[tid * 4] + redQ[tid * 4 + 1] + redQ[tid * 4 + 2] + redQ[tid * 4 + 3];
            float mean = s * (1.f / 256.f);
            float var = q * (1.f / 256.f) - mean * mean;
            meanl[tid] = mean;
            invl[tid] = rsqrtf(var + 1e-5f);
        }
        __syncthreads();
#pragma unroll
        for (int rb = 0; rb < 4; rb++) {
#pragma unroll
            for (int j = 0; j < 4; j++) {
                int r = rb * 16 + l4 * 4 + j;
                int nd = nid[r];
                if (nd < 0) continue;
                float mean = meanl[r], inv = invl[r];
#pragma unroll
                for (int cb = 0; cb < 4; cb++) {
                    int col = colbase + cb * 16 + l15;
                    float o = (acc[rb][cb][j] - mean) * inv * lng[t * 256 + col] + lnb[t * 256 + col];
                    if (out_f32) out_f32[(size_t)nd * 256 + col] = o;
                    out_bf[(size_t)nd * 256 + col] = f2b(o);
                }
            }
        }
    }
}

// fused k/q/v: stage A once, run 3 weight sets
__global__ __launch_bounds__(256) void k_gemm3(
    const unsigned short* __restrict__ Abf,
    const unsigned short* __restrict__ Wt0, const unsigned short* __restrict__ Wt1,
    const unsigned short* __restrict__ Wt2,
    const float* __restrict__ b0, const float* __restrict__ b1, const float* __restrict__ b2,
    const int* __restrict__ nlist, const int* __restrict__ toff,
    unsigned short* __restrict__ o0, unsigned short* __restrict__ o1,
    unsigned short* __restrict__ o2)
{
    __shared__ unsigned short A_l[64 * LDA];
    __shared__ int nid[64];

    int t = blockIdx.y;
    int g0 = toff[t], g1 = toff[t + 1];
    int base = blockIdx.x * 64;
    int cnt = g1 - g0 - base;
    if (cnt <= 0) return;
    if (cnt > 64) cnt = 64;
    int tid = threadIdx.x;
    if (tid < 64) nid[tid] = (tid < cnt) ? nlist[g0 + base + tid] : -1;
    __syncthreads();

#pragma unroll
    for (int it = 0; it < 8; it++) {
        int id = it * 256 + tid;
        int row = id >> 5, c8 = id & 31;
        short8 v = {};
        int nd = nid[row];
        if (nd >= 0) v = *(const short8*)(Abf + (size_t)nd * 256 + c8 * 8);
        *(short8*)(A_l + row * LDA + c8 * 8) = v;
    }
    __syncthreads();

    int lane = tid & 63, wave = tid >> 6;
    int colbase = wave * 64;
    int l15 = lane & 15, l4 = lane >> 4;
    const unsigned short* Wts[3] = {Wt0, Wt1, Wt2};
    const float* bs[3] = {b0, b1, b2};
    unsigned short* os[3] = {o0, o1, o2};
#pragma unroll
    for (int w = 0; w < 3; w++) {
        f32x4 acc[4][4];
        gemm_core(A_l, Wts[w] + (size_t)t * 65536, colbase, l15, l4, acc);
#pragma unroll
        for (int rb = 0; rb < 4; rb++) {
#pragma unroll
            for (int j = 0; j < 4; j++) {
                int r = rb * 16 + l4 * 4 + j;
                int nd = nid[r];
                if (nd < 0) continue;
#pragma unroll
                for (int cb = 0; cb < 4; cb++) {
                    int col = colbase + cb * 16 + l15;
                    os[w][(size_t)nd * 256 + col] = f2b(acc[rb][cb][j] + bs[w][t * 256 + col]);
                }
            }
        }
    }
}

// ---------- relation transform (q and v in one dispatch via z) ----------
__global__ __launch_bounds__(256) void k_rt(
    const unsigned short* __restrict__ qb, const unsigned short* __restrict__ vb,
    const unsigned short* __restrict__ relA, const unsigned short* __restrict__ relMT,
    unsigned short* __restrict__ qrt, unsigned short* __restrict__ vrt)
{
    int tid = threadIdx.x;
    int lane = tid & 63, wave = tid >> 6;
    int l15 = lane & 15, l4 = lane >> 4;
    int h = blockIdx.y;
    int n = blockIdx.x * 64 + wave * 16 + l15;
    const unsigned short* inb = blockIdx.z ? vb : qb;
    const unsigned short* rel = blockIdx.z ? relMT : relA;
    unsigned short* outrt = blockIdx.z ? vrt : qrt;
    short8 bfrag = {};
    if (n < NN) bfrag = *(const short8*)(inb + (size_t)n * 256 + h * 32 + 8 * l4);
#pragma unroll
    for (int r = 0; r < RR; r++) {
        const unsigned short* ap = rel + ((size_t)(r * HH + h)) * 1024;
        short8 a0 = *(const short8*)(ap + l15 * 32 + 8 * l4);
        short8 a1 = *(const short8*)(ap + (16 + l15) * 32 + 8 * l4);
        f32x4 c0 = {0.f, 0.f, 0.f, 0.f}, c1 = {0.f, 0.f, 0.f, 0.f};
        c0 = __builtin_amdgcn_mfma_f32_16x16x32_bf16(a0, bfrag, c0, 0, 0, 0);
        c1 = __builtin_amdgcn_mfma_f32_16x16x32_bf16(a1, bfrag, c1, 0, 0, 0);
        if (n < NN) {
            size_t ob = (((size_t)n * RR + r) * HH + h) * 32;
            us4 p0, p1;
#pragma unroll
            for (int j = 0; j < 4; j++) { p0[j] = f2b(c0[j]); p1[j] = f2b(c1[j]); }
            *(us4*)(outrt + ob + l4 * 4) = p0;
            *(us4*)(outrt + ob + 16 + l4 * 4) = p1;
        }
    }
}

// ---------- edge scores over CSR positions (coalesced writes) ----------
__global__ void k_score(const unsigned short* __restrict__ kbf,
                        const unsigned short* __restrict__ qrt,
                        const int4* __restrict__ csr, const float* __restrict__ pri,
                        float* __restrict__ sc)
{
    int idx = blockIdx.x * 256 + threadIdx.x;
    if (idx >= EE * HH) return;
    int p = idx >> 3, h = idx & 7;
    int4 pk = csr[p];
    int s = pk.x & 0xffff, r = (pk.x >> 16) & 7;
    float w = __int_as_float(pk.y);
    int d = pk.z;
    const short8* kp = (const short8*)(kbf + (size_t)s * 256 + h * 32);
    const short8* qp = (const short8*)(qrt + (((size_t)d * RR + r) * HH + h) * 32);
    float acc = 0.f;
#pragma unroll
    for (int c = 0; c < 4; c++) {
        short8 a = kp[c], b = qp[c];
#pragma unroll
        for (int j = 0; j < 8; j++)
            acc += b2f((unsigned short)a[j]) * b2f((unsigned short)b[j]);
    }
    sc[idx] = acc * pri[r * HH + h] * 0.17677669529663687f * w;
}

// ---------- per-dst softmax + aggregate + gelu (round-3 structure) ----------
__global__ __launch_bounds__(256) void k_agg(
    const float* __restrict__ sc, const unsigned short* __restrict__ vrt,
    const int4* __restrict__ csr, const int* __restrict__ off,
    unsigned short* __restrict__ gbf, float* __restrict__ smaxg, float* __restrict__ ssumg)
{
    __shared__ float p_l[32][9];
    __shared__ int sv[32], se[32];
    int n = blockIdx.x;
    int tid = threadIdx.x;
    int h = tid >> 5, i = tid & 31;
    int t0 = off[n], cnt = off[n + 1] - t0;

    float smax = -INFINITY;
    for (int ii = i; ii < cnt; ii += 32)
        smax = fmaxf(smax, sc[(size_t)(t0 + ii) * 8 + h]);
#pragma unroll
    for (int m = 16; m >= 1; m >>= 1) smax = fmaxf(smax, __shfl_xor(smax, m, 32));

    float psum = 0.f, agg = 0.f;
    for (int c0 = 0; c0 < cnt; c0 += 32) {
        int m = cnt - c0;
        if (m > 32) m = 32;
        __syncthreads();
        if (tid < m) {
            int4 pk = csr[t0 + c0 + tid];
            sv[tid] = pk.x & 0xffff;
            se[tid] = (pk.x >> 16) & 7;
        }
        __syncthreads();
        if (i < m) {
            float p = __expf(sc[(size_t)(t0 + c0 + i) * 8 + h] - smax);
            p_l[i][h] = p;
            psum += p;
        }
        // no barrier: producer/consumer of p_l[.][h] share a 32-lane group
        for (int ii = 0; ii < m; ii++) {
            float p = p_l[ii][h];
            agg += p * b2f(vrt[(((size_t)sv[ii] * RR + se[ii]) * HH + h) * 32 + i]);
        }
    }
#pragma unroll
    for (int m = 16; m >= 1; m >>= 1) psum += __shfl_xor(psum, m, 32);
    if (i == 0) { smaxg[n * 8 + h] = smax; ssumg[n * 8 + h] = psum; }
    float den = psum + 1e-9f;
    float a = agg / den;
    float g = 0.5f * a * (1.f + tanhf(0.7978845608028654f * (a + 0.044715f * a * a * a)));
    gbf[(size_t)n * 256 + tid] = f2b(g);
}

// ---------- attention output over CSR positions (last layer) ----------
__global__ void k_att(const float* __restrict__ sc, const int4* __restrict__ csr,
                      const float* __restrict__ smaxg, const float* __restrict__ ssumg,
                      float* __restrict__ att)
{
    int idx = blockIdx.x * 256 + threadIdx.x;
    if (idx >= EE * HH) return;
    int p = idx >> 3, h = idx & 7;
    int4 pk = csr[p];
    int d = pk.z, e = pk.w;
    att[(size_t)e * 8 + h] = __expf(sc[idx] - smaxg[d * 8 + h]) / (ssumg[d * 8 + h] + 1e-9f);
}

extern "C" void kernel_launch(void* const* d_in, const int* in_sizes, int n_in,
                              void* d_out, int out_size, void* d_ws, size_t ws_size,
                              hipStream_t stream)
{
    const float* nf = (const float*)d_in[0];
    const int* ntyp = (const int*)d_in[1];
    const float* ew = (const float*)d_in[2];
    const int* ei = (const int*)d_in[3];
    const int* ety = (const int*)d_in[4];
    const float* adW = (const float*)d_in[5];
    const float* adb = (const float*)d_in[6];
    const float* kW = (const float*)d_in[7];
    const float* kb = (const float*)d_in[8];
    const float* qW = (const float*)d_in[9];
    const float* qb = (const float*)d_in[10];
    const float* vW = (const float*)d_in[11];
    const float* vb = (const float*)d_in[12];
    const float* aW = (const float*)d_in[13];
    const float* ab = (const float*)d_in[14];
    const float* pri = (const float*)d_in[15];
    const float* rA = (const float*)d_in[16];
    const float* rM = (const float*)d_in[17];
    const float* skp = (const float*)d_in[18];
    const float* lng = (const float*)d_in[19];
    const float* lnb = (const float*)d_in[20];

    float* x_out = (float*)d_out;
    float* att_out = x_out + (size_t)NN * 256;

    char* wsb = (char*)d_ws;
    size_t o = 0;
    auto take = [&](size_t bytes) -> void* {
        size_t r = (o + 255) & ~(size_t)255;
        o = r + bytes;
        return (void*)(wsb + r);
    };
    unsigned short* nf_bf = (unsigned short*)take((size_t)NN * 256 * 2);
    unsigned short* x_bf = (unsigned short*)take((size_t)NN * 256 * 2);
    unsigned short* kb16 = (unsigned short*)take((size_t)NN * 256 * 2);
    unsigned short* qb16 = (unsigned short*)take((size_t)NN * 256 * 2);
    unsigned short* vb16 = (unsigned short*)take((size_t)NN * 256 * 2);
    unsigned short* gb16 = (unsigned short*)take((size_t)NN * 256 * 2);
    unsigned short* qrt = (unsigned short*)take((size_t)NN * RR * HH * 32 * 2);
    unsigned short* vrt = (unsigned short*)take((size_t)NN * RR * HH * 32 * 2);
    float* scores = (float*)take((size_t)EE * HH * 4);
    float* smaxg = (float*)take((size_t)NN * HH * 4);
    float* ssumg = (float*)take((size_t)NN * HH * 4);
    unsigned short* Wt_all = (unsigned short*)take((size_t)72 * 65536 * 2);
    unsigned short* adWt = Wt_all;
    unsigned short* kWt = Wt_all + (size_t)8 * 65536;
    unsigned short* qWt = Wt_all + (size_t)24 * 65536;
    unsigned short* vWt = Wt_all + (size_t)40 * 65536;
    unsigned short* aWt = Wt_all + (size_t)56 * 65536;
    unsigned short* relA = (unsigned short*)take((size_t)RELN * 2);
    unsigned short* relMT = (unsigned short*)take((size_t)RELN * 2);
    int* zblock = (int*)take((size_t)(NN + 2 * TT) * 4);
    int* deg = zblock;
    int* tcnt = zblock + NN;
    int* tcur = zblock + NN + TT;
    int* rank = (int*)take((size_t)EE * 4);
    int* off = (int*)take((size_t)(NN + 1) * 4);
    int4* csr = (int4*)take((size_t)EE * 16);
    int* toff = (int*)take((TT + 1) * 4);
    int* nlist = (int*)take((size_t)NN * 4);
    if (o > ws_size) return;  // workspace insufficient — fail visibly

    hipMemsetAsync(zblock, 0, (size_t)(NN + 2 * TT) * 4, stream);

    int ptot = NN * 256 + 2 * RELN;
    k_prep<<<(ptot + 255) / 256, 256, 0, stream>>>(nf, rA, rM, nf_bf, relA, relMT);
    k_transpose_all<<<dim3(8, 8, 72), dim3(32, 8), 0, stream>>>(adW, kW, qW, vW, aW, Wt_all);

    k_build1<<<(EE + 255) / 256, 256, 0, stream>>>(ei, ntyp, deg, tcnt, rank);
    k_scan<<<1, 256, 0, stream>>>(deg, off, tcnt, toff);
    k_build2<<<(EE + 255) / 256, 256, 0, stream>>>(ei, ety, ew, ntyp, off, toff, rank,
                                                   tcur, csr, nlist);

    dim3 ggrid((NN + 63) / 64, TT);
    k_gemm<0><<<ggrid, 256, 0, stream>>>(nf_bf, adWt, adb, nlist, toff,
                                         x_bf, nullptr, nullptr, nullptr, nullptr, nullptr);

    dim3 rgrid((NN + 63) / 64, HH, 2);
    int egrid = (EE * HH + 255) / 256;
    for (int l = 0; l < LLAYERS; l++) {
        k_gemm3<<<ggrid, 256, 0, stream>>>(x_bf,
                                           kWt + (size_t)l * TT * 65536, qWt + (size_t)l * TT * 65536,
                                           vWt + (size_t)l * TT * 65536,
                                           kb + (size_t)l * TT * 256, qb + (size_t)l * TT * 256,
                                           vb + (size_t)l * TT * 256,
                                           nlist, toff, kb16, qb16, vb16);
        k_rt<<<rgrid, 256, 0, stream>>>(qb16, vb16,
                                        relA + (size_t)l * RR * HH * 1024,
                                        relMT + (size_t)l * RR * HH * 1024, qrt, vrt);
        k_score<<<egrid, 256, 0, stream>>>(kb16, qrt, csr, pri + (size_t)l * RR * HH, scores);
        k_agg<<<NN, 256, 0, stream>>>(scores, vrt, csr, off, gb16, smaxg, ssumg);
        if (l == LLAYERS - 1)
            k_att<<<egrid, 256, 0, stream>>>(scores, csr, smaxg, ssumg, att_out);
        k_gemm<2><<<ggrid, 256, 0, stream>>>(gb16, aWt + (size_t)l * TT * 65536, ab + (size_t)l * TT * 256,
                                             nlist, toff, x_bf,
                                             (l == LLAYERS - 1) ? x_out : nullptr,
                                             x_bf,
                                             skp + (size_t)l * TT, lng + (size_t)l * TT * 256, lnb + (size_t)l * TT * 256);
    }
}